// Round 1
// baseline (551.663 us; speedup 1.0000x reference)
//
#include <hip/hip_runtime.h>

#define Bk 16
#define Hk 256
#define Lk 8192
#define N2k 32
#define Sk 256
#define Gk (Lk / Sk) // 32

// Workspace layout (bytes):
//   W  (float2[H*N2])  @ 0        : w = exp(dt*A)
//   CT (float2[H*N2])  @ 65536    : 2*C*(w-1)/A
//   WS (float2[H*N2])  @ 131072   : w^S
//   F  (float2[B*H*G*N2]) @ 262144 : chunk end-states, overwritten in-place
//                                    with chunk init-states by pass B
// total ~33.8 MB

__global__ void s4d_precompute(const float* __restrict__ log_dt,
                               const float* __restrict__ log_A_real,
                               const float* __restrict__ A_imag,
                               const float* __restrict__ C,
                               float2* __restrict__ W,
                               float2* __restrict__ CT,
                               float2* __restrict__ WS) {
    int t = blockIdx.x * blockDim.x + threadIdx.x;
    if (t >= Hk * N2k) return;
    int h = t >> 5;
    double dt  = exp((double)log_dt[h]);
    double are = -exp((double)log_A_real[t]);
    double aim = (double)A_imag[t];
    double dr = dt * are, di = dt * aim;
    double er  = exp(dr);
    double wre = er * cos(di), wim = er * sin(di);
    // (w - 1) / A  =  (w-1) * conj(A) / |A|^2
    double denom = are * are + aim * aim;
    double tr = wre - 1.0, ti = wim;
    double qr = (tr * are + ti * aim) / denom;
    double qi = (ti * are - tr * aim) / denom;
    double c0 = (double)C[2 * t], c1 = (double)C[2 * t + 1];
    W[t]  = make_float2((float)wre, (float)wim);
    CT[t] = make_float2((float)(2.0 * (c0 * qr - c1 * qi)),
                        (float)(2.0 * (c0 * qi + c1 * qr)));
    double esr = exp((double)Sk * dr);
    double sdi = (double)Sk * di;
    WS[t] = make_float2((float)(esr * cos(sdi)), (float)(esr * sin(sdi)));
}

// Pass A: one thread per (b,h,c,n): local end-state of chunk c with zero init.
__global__ __launch_bounds__(256) void s4d_passA(const float* __restrict__ u,
                                                 const float2* __restrict__ W,
                                                 const float2* __restrict__ CT,
                                                 float2* __restrict__ F) {
    int t = blockIdx.x * blockDim.x + threadIdx.x; // [0, B*H*G*N2)
    int n = t & (N2k - 1);
    int c = (t >> 5) & (Gk - 1);
    int rest = t >> 10;            // b*H + h
    int h = rest & (Hk - 1);
    float2 w  = W[(h << 5) | n];
    float2 ct = CT[(h << 5) | n];
    const float4* up = (const float4*)(u + (size_t)rest * Lk + (size_t)c * Sk);
    float zr = 0.f, zi = 0.f;
    #pragma unroll 4
    for (int j = 0; j < Sk / 4; ++j) {
        float4 uv = up[j];
        float us[4] = {uv.x, uv.y, uv.z, uv.w};
        #pragma unroll
        for (int k = 0; k < 4; ++k) {
            float zr2 = fmaf(w.x, zr, fmaf(-w.y, zi, ct.x * us[k]));
            float zi2 = fmaf(w.x, zi, fmaf(w.y, zr, ct.y * us[k]));
            zr = zr2; zi = zi2;
        }
    }
    F[t] = make_float2(zr, zi); // layout [rest][c][n] == t order
}

// Pass B: one thread per (b,h,n): exclusive scan over chunks with mult w^S.
// In-place: F[rest][c][n] becomes the init state I for chunk c.
__global__ __launch_bounds__(256) void s4d_passB(const float2* __restrict__ WS,
                                                 float2* __restrict__ F) {
    int t = blockIdx.x * blockDim.x + threadIdx.x; // [0, B*H*N2)
    int n = t & (N2k - 1);
    int rest = t >> 5;             // b*H + h
    int h = rest & (Hk - 1);
    float2 ws = WS[(h << 5) | n];
    float zr = 0.f, zi = 0.f;
    #pragma unroll
    for (int c = 0; c < Gk; ++c) {
        int idx = (((rest << 5) + c) << 5) | n; // (rest*G + c)*N2 + n
        float2 f = F[idx];
        F[idx] = make_float2(zr, zi);
        float zr2 = fmaf(ws.x, zr, -ws.y * zi) + f.x;
        float zi2 = fmaf(ws.x, zi,  ws.y * zr) + f.y;
        zr = zr2; zi = zi2;
    }
}

// Pass C: one thread per (b,h,c), all 32 complex states in registers,
// seeded from I; emits y for its chunk.
__global__ __launch_bounds__(256) void s4d_passC(const float* __restrict__ u,
                                                 const float2* __restrict__ W,
                                                 const float2* __restrict__ CT,
                                                 const float2* __restrict__ F,
                                                 const float* __restrict__ Dv,
                                                 float* __restrict__ y) {
    int t = blockIdx.x * blockDim.x + threadIdx.x; // [0, B*H*G)
    int c = t & (Gk - 1);
    int rest = t >> 5;             // b*H + h
    int h = rest & (Hk - 1);

    float wre[N2k], wim[N2k], ctre[N2k], ctim[N2k], zr[N2k], zi[N2k];
    #pragma unroll
    for (int n = 0; n < N2k; ++n) {
        float2 w  = W[(h << 5) | n];
        float2 cc = CT[(h << 5) | n];
        float2 z0 = F[(((rest << 5) + c) << 5) | n];
        wre[n] = w.x;  wim[n] = w.y;
        ctre[n] = cc.x; ctim[n] = cc.y;
        zr[n] = z0.x;  zi[n] = z0.y;
    }
    float Dh = Dv[h];
    size_t base = (size_t)rest * Lk + (size_t)c * Sk;
    const float4* up = (const float4*)(u + base);
    float4* yp = (float4*)(y + base);
    for (int j = 0; j < Sk / 4; ++j) {
        float4 uv = up[j];
        float us[4] = {uv.x, uv.y, uv.z, uv.w};
        float outs[4];
        #pragma unroll
        for (int k = 0; k < 4; ++k) {
            float uval = us[k];
            float acc = Dh * uval;
            #pragma unroll
            for (int n = 0; n < N2k; ++n) {
                float zr2 = fmaf(wre[n], zr[n], fmaf(-wim[n], zi[n], ctre[n] * uval));
                float zi2 = fmaf(wre[n], zi[n], fmaf( wim[n], zr[n], ctim[n] * uval));
                zr[n] = zr2; zi[n] = zi2;
                acc += zr2;
            }
            outs[k] = acc;
        }
        float4 yv; yv.x = outs[0]; yv.y = outs[1]; yv.z = outs[2]; yv.w = outs[3];
        yp[j] = yv;
    }
}

extern "C" void kernel_launch(void* const* d_in, const int* in_sizes, int n_in,
                              void* d_out, int out_size, void* d_ws, size_t ws_size,
                              hipStream_t stream) {
    const float* u           = (const float*)d_in[0];
    const float* log_dt      = (const float*)d_in[1];
    const float* log_A_real  = (const float*)d_in[2];
    const float* A_imag      = (const float*)d_in[3];
    const float* C           = (const float*)d_in[4];
    const float* D           = (const float*)d_in[5];
    float* y = (float*)d_out;

    char* ws = (char*)d_ws;
    float2* W  = (float2*)(ws);
    float2* CT = (float2*)(ws + 65536);
    float2* WS = (float2*)(ws + 131072);
    float2* F  = (float2*)(ws + 262144);

    s4d_precompute<<<(Hk * N2k) / 256, 256, 0, stream>>>(log_dt, log_A_real,
                                                         A_imag, C, W, CT, WS);
    s4d_passA<<<(Bk * Hk * Gk * N2k) / 256, 256, 0, stream>>>(u, W, CT, F);
    s4d_passB<<<(Bk * Hk * N2k) / 256, 256, 0, stream>>>(WS, F);
    s4d_passC<<<(Bk * Hk * Gk) / 256, 256, 0, stream>>>(u, W, CT, F, D, y);
}